// Round 1
// baseline (294.590 us; speedup 1.0000x reference)
//
#include <hip/hip_runtime.h>

// out[b,i,h,j] = x[b,0,h,j+i] * z[b,0,h,j], zero where j+i >= W.
// B=4, H=512, W=2048, WC=16. fp32 in/out.
// Write-BW-bound: 256 MiB out + 32 MiB in => ~46 us floor at 6.3 TB/s.

#define B_ 4
#define H_ 512
#define W_ 2048
#define WC_ 16

__global__ __launch_bounds__(256) void
space2features_kernel(const float* __restrict__ x,
                      const float* __restrict__ z,
                      float* __restrict__ out) {
    // One thread per 4 consecutive j. Total threads: B*H*(W/4) = 1,048,576.
    const int tid = blockIdx.x * blockDim.x + threadIdx.x;
    const int JV = W_ / 4;                  // 512 float4 slots per row
    const int jv = tid & (JV - 1);          // JV is pow2
    const int bh = tid >> 9;                // tid / JV ; b*H + h
    if (bh >= B_ * H_) return;
    const int j = jv * 4;

    const float* xrow = x + (size_t)bh * W_;
    const float* zrow = z + (size_t)bh * W_;

    const float4 z4 = *(const float4*)(zrow + j);

    // Sliding window x[j .. j+19] covers all 16 shifts for 4 outputs.
    float xr[20];
    const long long gbase = (long long)bh * W_ + j;
    const long long total = (long long)B_ * H_ * W_;
    if (gbase + 20 <= total) {
        // Fast path: 5 aligned float4 loads. May read into the next row;
        // those values are provably masked out (used only where j+m >= W).
#pragma unroll
        for (int k = 0; k < 5; ++k) {
            float4 t = *(const float4*)(xrow + j + 4 * k);
            xr[4 * k + 0] = t.x;
            xr[4 * k + 1] = t.y;
            xr[4 * k + 2] = t.z;
            xr[4 * k + 3] = t.w;
        }
    } else {
        // Buffer-tail path (last wave of the grid only).
#pragma unroll
        for (int k = 0; k < 20; ++k) {
            xr[k] = (gbase + k < total) ? xrow[j + k] : 0.0f;
        }
    }

    const int b = bh >> 9;          // bh / H_
    const int h = bh & (H_ - 1);    // bh % H_
    // out index: ((b*WC + i)*H + h)*W + j
    float* obase = out + (((size_t)b * WC_) * H_ + h) * (size_t)W_ + j;

#pragma unroll
    for (int i = 0; i < WC_; ++i) {
        float4 o;
        o.x = (j + 0 + i < W_) ? xr[i + 0] * z4.x : 0.0f;
        o.y = (j + 1 + i < W_) ? xr[i + 1] * z4.y : 0.0f;
        o.z = (j + 2 + i < W_) ? xr[i + 2] * z4.z : 0.0f;
        o.w = (j + 3 + i < W_) ? xr[i + 3] * z4.w : 0.0f;
        *(float4*)(obase + (size_t)i * (H_ * W_)) = o;
    }
}

extern "C" void kernel_launch(void* const* d_in, const int* in_sizes, int n_in,
                              void* d_out, int out_size, void* d_ws, size_t ws_size,
                              hipStream_t stream) {
    const float* x = (const float*)d_in[0];
    const float* z = (const float*)d_in[1];
    float* out = (float*)d_out;

    const int total_threads = B_ * H_ * (W_ / 4);   // 1,048,576
    const int block = 256;
    const int grid = (total_threads + block - 1) / block;  // 4096
    space2features_kernel<<<grid, block, 0, stream>>>(x, z, out);
}